// Round 7
// baseline (356.621 us; speedup 1.0000x reference)
//
#include <hip/hip_runtime.h>
#include <math.h>

#define NSTEP  730
#define NGRID  1500
#define LENF   15
#define PRECS  1e-5f
#define CH     16
#define NCHUNK ((NSTEP + CH - 1)/CH)   // 46 (45 full chunks + tail of 10)
#define XROW   12                      // dwords of x per step (4 grids * 3 ch)
#define XBUFDW (CH*XROW)               // 192
#define QROW   260                     // 256 + 4 pad (bank-clean read side)
#define QTOT   (CH*QROW)               // 4160
#define RQL    (LENF-1+NSTEP)          // 744
#define OTW    21                      // out-tile row width (20 + 1 pad)

// Block = 128 threads = 2 waves, 4 grids (16 mu each), 375 blocks.
// Wave 0 (producer): pure state-chain scan; per step = 3 broadcast ds_read
//   + ~40 VALU + 1 ds_write_b128. Nothing else.
// Wave 1 (consumer): lags one chunk; stages x (double-buffered), reduces the
//   q-tile over mu, computes routing conv online, assembles [CH][20] out-tile,
//   stores it coalesced. One __syncthreads per chunk.
__global__ __launch_bounds__(128, 1)
void hbv_scan_kernel(const float* __restrict__ x,       // (730,1500,3)
                     const float* __restrict__ params,  // (1500,12,16)
                     const float* __restrict__ rtwts,   // (1500,2)
                     float* __restrict__ out)           // (730,1500,5)
{
    __shared__ float xbuf[2*XBUFDW];      //  1.5 KB
    __shared__ float qbuf[2*QTOT];        // 33.3 KB
    __shared__ float rqbuf[4*RQL];        // 11.9 KB
    __shared__ float outtile[CH*OTW];     //  1.3 KB   (total 48.1 KB)

    const int tid  = threadIdx.x;
    const int wid  = tid >> 6;
    const int lane = tid & 63;
    const int gl   = lane >> 4;
    const int m    = lane & 15;
    const int g    = blockIdx.x*4 + gl;
    const int G3   = blockIdx.x*12;
    const float inv16 = 1.f/16.f;

    // zero the 14-entry conv-history pad of each grid slot
    if (tid < 4*(LENF-1)) {
        const int q = tid/(LENF-1), r = tid - q*(LENF-1);
        rqbuf[q*RQL + r] = 0.f;
    }

    // ---- per-wave one-time setup ----
    float pBETA=0,pFC=0,pK0=0,pK1=0,pK2=0,pPERC=0,pUZL=0,pTT=0,pCFMAX=0,pCWH=0;
    float invFC=0, invLPFC=0, refCoef=0, negCMTT=0, refCTT=0;
    float SNOWPACK=0, MELTWATER=0, SM=0, SUZ=0, SLZ=0;
    float wq[LENF];
    int xrow[3], xcol[3], st_o[5], st_g[5];

    if (wid == 0) {
        const float lo[12] = {1.f, 50.f, 0.05f, 0.01f, 0.001f, 0.2f, 0.f, 0.f, -2.5f, 0.5f, 0.f, 0.f};
        const float hi[12] = {6.f, 1000.f, 0.9f, 0.5f, 0.2f, 1.f, 10.f, 100.f, 2.5f, 10.f, 0.1f, 0.2f};
        float p[12];
        #pragma unroll
        for (int i = 0; i < 12; ++i)
            p[i] = lo[i] + params[(g*12 + i)*16 + m] * (hi[i] - lo[i]);
        pBETA=p[0]; pFC=p[1]; pK0=p[2]; pK1=p[3]; pK2=p[4];
        pPERC=p[6]; pUZL=p[7]; pTT=p[8]; pCFMAX=p[9]; pCWH=p[11];
        invFC   = 1.f / pFC;
        invLPFC = 1.f / (p[5] * pFC);
        refCoef = p[10] * pCFMAX;
        negCMTT = -pCFMAX * pTT;
        refCTT  = refCoef * pTT;
        SNOWPACK = MELTWATER = SM = SUZ = SLZ = 0.001f;
    } else {
        // routing weights (uniform across the 16 lanes of each gl group)
        const float ta  = rtwts[g*2+0] * 2.9f;
        const float tbv = rtwts[g*2+1] * 6.5f;
        const float aa = fmaxf(ta, 0.f) + 0.1f;
        const float th = fmaxf(tbv, 0.f) + 0.5f;
        const float c0v = expf(-lgammaf(aa)) * powf(th, -aa);
        float wsum = 0.f;
        #pragma unroll
        for (int k = 0; k < LENF; ++k) {
            const float tt = (float)k + 0.5f;
            wq[k] = c0v * powf(tt, aa - 1.f) * expf(-tt / th);
            wsum += wq[k];
        }
        const float wscale = inv16 / wsum;     // fold /16 + normalization
        #pragma unroll
        for (int k = 0; k < LENF; ++k) wq[k] *= wscale;

        // x staging map (3 dwords/lane per chunk) + pre-stage chunk 0
        #pragma unroll
        for (int j = 0; j < 3; ++j) {
            const int idx = lane + 64*j;
            xrow[j] = idx / 12; xcol[j] = idx - xrow[j]*12;
        }
        #pragma unroll
        for (int j = 0; j < 3; ++j) {
            const int idx = lane + 64*j;
            xbuf[idx] = x[xrow[j]*4500 + G3 + xcol[j]];
        }
        // coalesced-store map (5 insts cover CH*20 = 320 dwords)
        #pragma unroll
        for (int j = 0; j < 5; ++j) {
            const int idx = lane + 64*j;
            const int t = idx / 20, cl = idx - 20*t;
            st_o[j] = t*OTW + cl;
            st_g[j] = t*7500 + cl;
        }
    }
    __syncthreads();

    for (int c = 0; c <= NCHUNK; ++c) {
        if (wid == 0) {
            // ================= producer: scan chunk c =================
            if (c < NCHUNK) {
                const int nstep = (NSTEP - c*CH < CH) ? (NSTEP - c*CH) : CH;
                const float* xb = &xbuf[(c&1)*XBUFDW + gl*3];
                float* qb = &qbuf[(c&1)*QTOT + lane*4];

                auto do_step = [&](int s) {
                    const float Pm = xb[s*XROW + 0];
                    const float Tm = xb[s*XROW + 1];
                    const float Em = xb[s*XROW + 2];

                    const float RAIN    = (Tm >= pTT) ? Pm : 0.f;
                    const float SNOW    = Pm - RAIN;
                    const float meltcap = fmaxf(fmaf(pCFMAX, Tm, negCMTT), 0.f);
                    const float refcap  = fmaxf(fmaf(-refCoef, Tm, refCTT), 0.f);

                    SNOWPACK += SNOW;
                    const float melt = fminf(meltcap, SNOWPACK);
                    MELTWATER += melt;
                    SNOWPACK -= melt;
                    const float refreeze = fminf(refcap, MELTWATER);
                    SNOWPACK += refreeze;
                    MELTWATER -= refreeze;
                    const float tosoil = fmaxf(fmaf(-pCWH, SNOWPACK, MELTWATER), 0.f);
                    MELTWATER -= tosoil;
                    const float sw = fminf(__powf(SM * invFC, pBETA), 1.f);
                    const float rt = RAIN + tosoil;
                    const float recharge = rt * sw;
                    SM = SM + rt - recharge;
                    const float excess = fmaxf(SM - pFC, 0.f);
                    SM -= excess;
                    const float evap = fminf(SM * invLPFC, 1.f);
                    const float ETact = fminf(SM, Em * evap);
                    SM = fmaxf(SM - ETact, PRECS);
                    SUZ += recharge + excess;
                    const float PERC = fminf(SUZ, pPERC);
                    SUZ -= PERC;
                    const float Q0 = pK0 * fmaxf(SUZ - pUZL, 0.f);
                    SUZ -= Q0;
                    const float Q1 = pK1 * SUZ;
                    SUZ -= Q1;
                    SLZ += PERC;
                    const float Q2 = pK2 * SLZ;
                    SLZ -= Q2;

                    float4 qv; qv.x = Q0; qv.y = Q1; qv.z = Q2; qv.w = ETact;
                    *(float4*)&qb[s*QROW] = qv;
                };
                if (nstep == CH) {
                    #pragma unroll
                    for (int s = 0; s < CH; ++s) do_step(s);
                } else {
                    for (int s = 0; s < nstep; ++s) do_step(s);
                }
            }
        } else {
            // ================= consumer: phase c =================
            const int cc = c + 1;                       // chunk to stage
            const bool do_stage = (cc < NCHUNK);
            float xs0=0.f, xs1=0.f, xs2=0.f;
            if (do_stage) {
                const int nd = ((NSTEP - cc*CH < CH) ? (NSTEP - cc*CH) : CH) * XROW;
                const float* xb = x + cc*CH*4500 + G3;
                xs0 = (lane       < nd) ? xb[xrow[0]*4500 + xcol[0]] : 0.f;
                xs1 = (lane + 64  < nd) ? xb[xrow[1]*4500 + xcol[1]] : 0.f;
                xs2 = (lane + 128 < nd) ? xb[xrow[2]*4500 + xcol[2]] : 0.f;
            }
            if (c >= 1) {
                // ---- reduce chunk c-1 over mu: task = (gl, s=m) ----
                const int c0 = c - 1;
                const int nstep = (NSTEP - c0*CH < CH) ? (NSTEP - c0*CH) : CH;
                const float* qb = &qbuf[(c0&1)*QTOT + m*QROW + gl*64];
                float a0=0.f, a1=0.f, a2=0.f, a3=0.f;
                if (m < nstep) {
                    #pragma unroll
                    for (int i = 0; i < 16; ++i) {
                        const float4 v = *(const float4*)&qb[i*4];
                        a0 += v.x; a1 += v.y; a2 += v.z; a3 += v.w;
                    }
                }
                // commit staged x while reduce results settle
                if (do_stage) {
                    float* xd = &xbuf[(cc&1)*XBUFDW];
                    xd[lane] = xs0; xd[lane+64] = xs1; xd[lane+128] = xs2;
                }
                // ---- online routing conv + out-tile assembly ----
                const int t = c0*CH + m;
                if (m < nstep) rqbuf[gl*RQL + (LENF-1) + t] = a0 + a1 + a2;
                asm volatile("s_waitcnt lgkmcnt(0)" ::: "memory");
                if (m < nstep) {
                    float acc = 0.f;
                    #pragma unroll
                    for (int k = 0; k < LENF; ++k)
                        acc += wq[k] * rqbuf[gl*RQL + (LENF-1) + t - k];
                    float* ot = &outtile[m*OTW + gl*5];
                    ot[0] = acc;
                    ot[1] = a0*inv16; ot[2] = a1*inv16;
                    ot[3] = a2*inv16; ot[4] = a3*inv16;
                }
                asm volatile("s_waitcnt lgkmcnt(0)" ::: "memory");
                // ---- coalesced store: contiguous 80B runs per (t, block) ----
                const int ndw = nstep*20;
                float* ob = out + c0*CH*7500 + blockIdx.x*20;
                #pragma unroll
                for (int j = 0; j < 5; ++j) {
                    const int idx = lane + 64*j;
                    if (idx < ndw) ob[st_g[j]] = outtile[st_o[j]];
                }
            } else if (do_stage) {
                float* xd = &xbuf[(cc&1)*XBUFDW];
                xd[lane] = xs0; xd[lane+64] = xs1; xd[lane+128] = xs2;
            }
        }
        __syncthreads();
    }
}

extern "C" void kernel_launch(void* const* d_in, const int* in_sizes, int n_in,
                              void* d_out, int out_size, void* d_ws, size_t ws_size,
                              hipStream_t stream)
{
    const float* x      = (const float*)d_in[0];
    const float* params = (const float*)d_in[1];
    const float* rt     = (const float*)d_in[2];
    float* out = (float*)d_out;

    dim3 grid(NGRID / 4), block(128);
    hipLaunchKernelGGL(hbv_scan_kernel, grid, block, 0, stream, x, params, rt, out);
}